// Round 17
// baseline (119.832 us; speedup 1.0000x reference)
//
#include <hip/hip_runtime.h>
#include <hip/hip_fp16.h>

#define NCELL 4096

typedef _Float16 f16x8 __attribute__((ext_vector_type(8)));
typedef float f32x4 __attribute__((ext_vector_type(4)));

__device__ __forceinline__ unsigned int packrn(float a, float b) {
    __half2 h = __floats2half2_rn(a, b);
    union { __half2 h; unsigned int u; } x; x.h = h; return x.u;
}

__device__ __forceinline__ int cell_of(float x0, float x1, float x2) {
    int i0 = (int)(x0 / 0.1875f + 8.0f);
    int i1 = (int)(x1 / 0.1875f + 8.0f);
    int i2 = (int)(x2 / 0.1875f + 8.0f);
    i0 = i0 < 0 ? 0 : (i0 > 15 ? 15 : i0);
    i1 = i1 < 0 ? 0 : (i1 > 15 ? 15 : i1);
    i2 = i2 < 0 ? 0 : (i2 > 15 ? 15 : i2);
    return (i0 * 16 + i1) * 16 + i2;
}

__global__ void k_count(const float* __restrict__ xs, int* __restrict__ counts,
                        int* __restrict__ cellid, float* __restrict__ out, int P) {
    int p = blockIdx.x * blockDim.x + threadIdx.x;
    if (p >= P) return;
    float x0 = xs[p * 3 + 0], x1 = xs[p * 3 + 1], x2 = xs[p * 3 + 2];
    bool m = (fabsf(x0) < 1.5f) && (fabsf(x1) < 1.5f) && (fabsf(x2) < 1.5f);
    if (m) {
        int c = cell_of(x0, x1, x2);
        cellid[p] = c;
        atomicAdd(&counts[c], 1);
    } else {
        cellid[p] = -1;
        out[p * 3 + 0] = 0.0f;
        out[p * 3 + 1] = 0.0f;
        out[p * 3 + 2] = 0.0f;
        out[3 * P + p] = 0.0f;
    }
}

__global__ void k_scan(const int* __restrict__ counts, int* __restrict__ offsets,
                       int* __restrict__ cursor) {
    int l = threadIdx.x;
    const int4* c4 = (const int4*)(counts + l * 64);
    int4 v[16];
#pragma unroll
    for (int k = 0; k < 16; k++) v[k] = c4[k];
    int s = 0;
#pragma unroll
    for (int k = 0; k < 16; k++) s += v[k].x + v[k].y + v[k].z + v[k].w;
    int incl = s;
    for (int d = 1; d < 64; d <<= 1) {
        int t = __shfl_up(incl, d, 64);
        if (l >= d) incl += t;
    }
    int run = incl - s;
#pragma unroll
    for (int k = 0; k < 16; k++) {
        int4 o;
        o.x = run; run += v[k].x;
        o.y = run; run += v[k].y;
        o.z = run; run += v[k].z;
        o.w = run; run += v[k].w;
        ((int4*)(offsets + l * 64))[k] = o;
        ((int4*)(cursor + l * 64))[k] = o;
    }
    if (l == 63) offsets[4096] = run;
}

__global__ void k_scatter(const int* __restrict__ cellid, int* __restrict__ cursor,
                          int* __restrict__ sorted, int P) {
    int p = blockIdx.x * blockDim.x + threadIdx.x;
    if (p >= P) return;
    int c = cellid[p];
    if (c < 0) return;
    int pos = atomicAdd(&cursor[c], 1);
    sorted[pos] = p;
}

// ---- encoding values, lane-local (k is the MFMA A-frag k index) ----
__device__ __forceinline__ float pe_val(int k, float x0, float x1, float x2) {
    float v;
    if (k < 3) v = (k == 0) ? x0 : ((k == 1) ? x1 : x2);
    else if (k < 63) {
        int q = k - 3, j = q / 6, r = q % 6, a = r % 3;
        float xx = (a == 0) ? x0 : ((a == 1) ? x1 : x2);
        float arg = (float)(1 << j) * xx;
        v = (r < 3) ? __sinf(arg) : __cosf(arg);
    } else v = 0.0f;
    return v;
}
__device__ __forceinline__ float de_val(int k, float d0, float d1, float d2) {
    float v;
    if (k < 3) v = (k == 0) ? d0 : ((k == 1) ? d1 : d2);
    else if (k < 27) {
        int q = k - 3, j = q / 6, r = q % 6, a = r % 3;
        float xx = (a == 0) ? d0 : ((a == 1) ? d1 : d2);
        float arg = (float)(1 << j) * xx;
        v = (r < 3) ? __sinf(arg) : __cosf(arg);
    } else v = 0.0f;
    return v;
}

// ---- MFMA helpers ----
__device__ __forceinline__ f16x8 ldB(const char* wb, int off, int blk, int lane) {
    return *(const f16x8*)(wb + off + blk * 1024 + lane * 16);
}
// act: [16 p][32 k] f16, row stride 64 B, XOR swizzle (p&3)<<4 (mask bits 4-5
// don't overlap the within-slot 2i bits -> read/write consistent).
__device__ __forceinline__ f16x8 ldA0(const char* act, int lane) {
    int p = lane & 15, g = lane >> 4;
    int byte = (p * 64 + g * 16) ^ ((p & 3) << 4);
    return *(const f16x8*)(act + byte);
}
__device__ __forceinline__ void stD0(char* act, int kcol, f32x4 acc, bool relu, int g4) {
#pragma unroll
    for (int r = 0; r < 4; r++) {
        int p = g4 * 4 + r;
        float v = acc[r];
        if (relu) v = fmaxf(v, 0.0f);
        *(_Float16*)(act + ((p * 64 + kcol * 2) ^ ((p & 3) << 4))) = (_Float16)v;
    }
}

// Batched staging (validated R12): phase 1 issues all independent global
// loads into compile-time-indexed registers; phase 2 packs + ds_writes.
template <int ITERS, int NKS>
__device__ __forceinline__ void stage_fragC(char* wb, int off,
                                            const float* __restrict__ W,
                                            int Krows, int Ncols, int stride,
                                            int tid) {
    float va[ITERS], vb[ITERS];
    unsigned int* dst = (unsigned int*)(wb + off);
#pragma unroll
    for (int j = 0; j < ITERS; j++) {
        int e = tid + 256 * j;
        int m = e & 3;
        int l = (e >> 2) & 63;
        int blk = e >> 8;
        int ks = blk % NKS;
        int n = blk / NKS;
        int c = l & 15, gg = l >> 4;
        int k0 = ks * 32 + gg * 8 + 2 * m;
        int col = 16 * n + c;
        int ka = (k0 < Krows) ? k0 : (Krows - 1);
        int kb = (k0 + 1 < Krows) ? (k0 + 1) : (Krows - 1);
        int cc = (col < Ncols) ? col : (Ncols - 1);
        va[j] = W[ka * stride + cc];
        vb[j] = W[kb * stride + cc];
    }
#pragma unroll
    for (int j = 0; j < ITERS; j++) {
        int e = tid + 256 * j;
        int m = e & 3;
        int l = (e >> 2) & 63;
        int blk = e >> 8;
        dst[blk * 256 + l * 4 + m] = packrn(va[j], vb[j]);
    }
}

#define MFMA16(a, b, c) __builtin_amdgcn_mfma_f32_16x16x32_f16((a), (b), (c), 0, 0, 0)

// 4 waves/block, one cell/block. Encoding A-frags built lane-locally in
// registers (no LDS round-trip); act LDS holds only layer outputs k 0..31
// (1 KB/wave). LDS/block ~19.6 KB -> 8 blocks/CU = 32 waves (max TLP).
__global__ void __launch_bounds__(256, 8) k_mlp(
    const float* __restrict__ xs, const float* __restrict__ dvs,
    const float* __restrict__ w1g, const float* __restrict__ b1g,
    const float* __restrict__ w2g, const float* __restrict__ b2g,
    const float* __restrict__ w3g, const float* __restrict__ b3g,
    const float* __restrict__ w4g, const float* __restrict__ b4g,
    const float* __restrict__ w5g, const float* __restrict__ b5g,
    const int* __restrict__ offsets, const int* __restrict__ sorted,
    float* __restrict__ out, int P) {
    __shared__ __align__(16) char wB[14336];
    __shared__ __align__(16) char actAll[4][1024];
    __shared__ float bias[160];
    __shared__ float sig[64];
    __shared__ int idxL[64];

    int cell = blockIdx.x;
    int start = offsets[cell], end = offsets[cell + 1];
    if (start >= end) return;
    int tid = threadIdx.x;
    int lane = tid & 63;
    int wid = tid >> 6;
    int cidx = lane & 15;
    int g4 = lane >> 4;

    stage_fragC<4, 2>(wB, 0,     w1g + (size_t)cell * 2016, 63, 32, 32, tid);
    stage_fragC<3, 1>(wB, 4096,  w2g + (size_t)cell * 1056, 32, 33, 33, tid);
    stage_fragC<2, 1>(wB, 7168,  w3g + (size_t)cell * 1024, 32, 32, 32, tid);
    stage_fragC<4, 2>(wB, 9216,  w4g + (size_t)cell * 1888, 59, 32, 32, tid);
    stage_fragC<1, 1>(wB, 13312, w5g + (size_t)cell * 96,   32, 3, 3, tid);
    if (tid < 160) {
        int e = tid;
        float v = 0.0f;
        if (e < 32) v = b1g[(size_t)cell * 32 + e];
        else if (e < 80) { int q = e - 32; v = (q < 33) ? b2g[(size_t)cell * 33 + q] : 0.0f; }
        else if (e < 112) v = b3g[(size_t)cell * 32 + (e - 80)];
        else if (e < 144) v = b4g[(size_t)cell * 32 + (e - 112)];
        else { int q = e - 144; v = (q < 3) ? b5g[(size_t)cell * 3 + q] : 0.0f; }
        bias[e] = v;
    }
    __syncthreads();

    char* buf = actAll[wid];
    float* sigw = sig + (wid << 4);
    int* idxw = idxL + (wid << 4);

    for (int t0 = start + (wid << 4); t0 < end; t0 += 64) {
        int nv = end - t0; if (nv > 16) nv = 16;
        int t = t0 + cidx;
        int idx = sorted[(cidx < nv) ? t : start];
        if (g4 == 0) idxw[cidx] = idx;
        float x0 = xs[idx * 3 + 0], x1 = xs[idx * 3 + 1], x2 = xs[idx * 3 + 2];
        float d0 = dvs[idx * 3 + 0], d1 = dvs[idx * 3 + 1], d2 = dvs[idx * 3 + 2];

        // ---- L1 A-frags built lane-locally: lane (cidx,g4) needs
        // enc[point cidx][k=8*g4+i] (a0) and [k=32+8*g4+i] (a1).
        f16x8 a0, a1;
#pragma unroll
        for (int i = 0; i < 8; i++) {
            a0[i] = (_Float16)pe_val(8 * g4 + i, x0, x1, x2);
            a1[i] = (_Float16)pe_val(32 + 8 * g4 + i, x0, x1, x2);
        }

        // ---- L1: enc(64) -> 32, relu -> buf k0..31
#pragma unroll
        for (int n = 0; n < 2; n++) {
            float bv = bias[0 + 16 * n + cidx];
            f32x4 acc = {bv, bv, bv, bv};
            acc = MFMA16(a0, ldB(wB, 0, n * 2 + 0, lane), acc);
            acc = MFMA16(a1, ldB(wB, 0, n * 2 + 1, lane), acc);
            stD0(buf, 16 * n + cidx, acc, true, g4);
        }

        // ---- L2: 32 -> 33, relu; col0 -> sigma; cols1..32 -> buf
        {
            f16x8 a2 = ldA0(buf, lane);
#pragma unroll
            for (int n = 0; n < 3; n++) {
                float bv = bias[32 + 16 * n + cidx];
                f32x4 acc = {bv, bv, bv, bv};
                acc = MFMA16(a2, ldB(wB, 4096, n, lane), acc);
                int C = 16 * n + cidx;
                if (C == 0) {
#pragma unroll
                    for (int r = 0; r < 4; r++) sigw[g4 * 4 + r] = fmaxf(acc[r], 0.0f);
                } else if (C <= 32) {
                    stD0(buf, C - 1, acc, true, g4);
                }
            }
        }
        // ---- L3: 32 -> 32, no act -> buf
        {
            f16x8 a3 = ldA0(buf, lane);
#pragma unroll
            for (int n = 0; n < 2; n++) {
                float bv = bias[80 + 16 * n + cidx];
                f32x4 acc = {bv, bv, bv, bv};
                acc = MFMA16(a3, ldB(wB, 7168, n, lane), acc);
                stD0(buf, 16 * n + cidx, acc, false, g4);
            }
        }
        // ---- L4: [h3 (LDS) | dir-enc (registers)] -> 32, relu -> buf
        {
            f16x8 a4a = ldA0(buf, lane);
            f16x8 a4b;
#pragma unroll
            for (int i = 0; i < 8; i++) a4b[i] = (_Float16)de_val(8 * g4 + i, d0, d1, d2);
#pragma unroll
            for (int n = 0; n < 2; n++) {
                float bv = bias[112 + 16 * n + cidx];
                f32x4 acc = {bv, bv, bv, bv};
                acc = MFMA16(a4a, ldB(wB, 9216, n * 2 + 0, lane), acc);
                acc = MFMA16(a4b, ldB(wB, 9216, n * 2 + 1, lane), acc);
                stD0(buf, 16 * n + cidx, acc, true, g4);
            }
        }
        // ---- L5: 32 -> 3, sigmoid; + sigma out
        {
            f16x8 a5 = ldA0(buf, lane);
            float bv = bias[144 + cidx];
            f32x4 acc = {bv, bv, bv, bv};
            acc = MFMA16(a5, ldB(wB, 13312, 0, lane), acc);
            if (cidx < 3) {
#pragma unroll
                for (int r = 0; r < 4; r++) {
                    int p = g4 * 4 + r;
                    if (p < nv) out[(size_t)idxw[p] * 3 + cidx] = 1.0f / (1.0f + __expf(-acc[r]));
                }
            } else if (cidx == 3) {
#pragma unroll
                for (int r = 0; r < 4; r++) {
                    int p = g4 * 4 + r;
                    if (p < nv) out[(size_t)3 * P + idxw[p]] = sigw[p];
                }
            }
        }
    }
}

extern "C" void kernel_launch(void* const* d_in, const int* in_sizes, int n_in,
                              void* d_out, int out_size, void* d_ws, size_t ws_size,
                              hipStream_t stream) {
    const float* xs = (const float*)d_in[0];
    const float* dv = (const float*)d_in[1];
    const float* w1 = (const float*)d_in[2];
    const float* b1 = (const float*)d_in[3];
    const float* w2 = (const float*)d_in[4];
    const float* b2 = (const float*)d_in[5];
    const float* w3 = (const float*)d_in[6];
    const float* b3 = (const float*)d_in[7];
    const float* w4 = (const float*)d_in[8];
    const float* b4 = (const float*)d_in[9];
    const float* w5 = (const float*)d_in[10];
    const float* b5 = (const float*)d_in[11];
    float* out = (float*)d_out;
    int P = in_sizes[0] / 3;

    int* counts = (int*)d_ws;
    int* offsets = counts + 4096;
    int* cursor = offsets + 4104;
    int* sorted = cursor + 4096;
    int* cellid = sorted + P;

    hipMemsetAsync(counts, 0, 4096 * sizeof(int), stream);

    int blk = 256;
    int grd = (P + blk - 1) / blk;
    k_count<<<grd, blk, 0, stream>>>(xs, counts, cellid, out, P);
    k_scan<<<1, 64, 0, stream>>>(counts, offsets, cursor);
    k_scatter<<<grd, blk, 0, stream>>>(cellid, cursor, sorted, P);
    k_mlp<<<NCELL, 256, 0, stream>>>(xs, dv, w1, b1, w2, b2, w3, b3, w4, b4, w5, b5,
                                     offsets, sorted, out, P);
}

// Round 18
// 72.416 us; speedup vs baseline: 1.6548x; 1.6548x over previous
//
#include <hip/hip_runtime.h>
#include <hip/hip_fp16.h>

#define NCELL 4096

typedef _Float16 f16x8 __attribute__((ext_vector_type(8)));
typedef float f32x4 __attribute__((ext_vector_type(4)));

__device__ __forceinline__ unsigned int packrn(float a, float b) {
    __half2 h = __floats2half2_rn(a, b);
    union { __half2 h; unsigned int u; } x; x.h = h; return x.u;
}

__device__ __forceinline__ int cell_of(float x0, float x1, float x2) {
    int i0 = (int)(x0 / 0.1875f + 8.0f);
    int i1 = (int)(x1 / 0.1875f + 8.0f);
    int i2 = (int)(x2 / 0.1875f + 8.0f);
    i0 = i0 < 0 ? 0 : (i0 > 15 ? 15 : i0);
    i1 = i1 < 0 ? 0 : (i1 > 15 ? 15 : i1);
    i2 = i2 < 0 ? 0 : (i2 > 15 ? 15 : i2);
    return (i0 * 16 + i1) * 16 + i2;
}

__global__ void k_count(const float* __restrict__ xs, int* __restrict__ counts,
                        int* __restrict__ cellid, float* __restrict__ out, int P) {
    int p = blockIdx.x * blockDim.x + threadIdx.x;
    if (p >= P) return;
    float x0 = xs[p * 3 + 0], x1 = xs[p * 3 + 1], x2 = xs[p * 3 + 2];
    bool m = (fabsf(x0) < 1.5f) && (fabsf(x1) < 1.5f) && (fabsf(x2) < 1.5f);
    if (m) {
        int c = cell_of(x0, x1, x2);
        cellid[p] = c;
        atomicAdd(&counts[c], 1);
    } else {
        cellid[p] = -1;
        out[p * 3 + 0] = 0.0f;
        out[p * 3 + 1] = 0.0f;
        out[p * 3 + 2] = 0.0f;
        out[3 * P + p] = 0.0f;
    }
}

__global__ void k_scan(const int* __restrict__ counts, int* __restrict__ offsets,
                       int* __restrict__ cursor) {
    int l = threadIdx.x;
    const int4* c4 = (const int4*)(counts + l * 64);
    int4 v[16];
#pragma unroll
    for (int k = 0; k < 16; k++) v[k] = c4[k];
    int s = 0;
#pragma unroll
    for (int k = 0; k < 16; k++) s += v[k].x + v[k].y + v[k].z + v[k].w;
    int incl = s;
    for (int d = 1; d < 64; d <<= 1) {
        int t = __shfl_up(incl, d, 64);
        if (l >= d) incl += t;
    }
    int run = incl - s;
#pragma unroll
    for (int k = 0; k < 16; k++) {
        int4 o;
        o.x = run; run += v[k].x;
        o.y = run; run += v[k].y;
        o.z = run; run += v[k].z;
        o.w = run; run += v[k].w;
        ((int4*)(offsets + l * 64))[k] = o;
        ((int4*)(cursor + l * 64))[k] = o;
    }
    if (l == 63) offsets[4096] = run;
}

__global__ void k_scatter(const int* __restrict__ cellid, int* __restrict__ cursor,
                          int* __restrict__ sorted, int P) {
    int p = blockIdx.x * blockDim.x + threadIdx.x;
    if (p >= P) return;
    int c = cellid[p];
    if (c < 0) return;
    int pos = atomicAdd(&cursor[c], 1);
    sorted[pos] = p;
}

// ---- encoding values, lane-local (k is the MFMA A-frag k index) ----
__device__ __forceinline__ float pe_val(int k, float x0, float x1, float x2) {
    float v;
    if (k < 3) v = (k == 0) ? x0 : ((k == 1) ? x1 : x2);
    else if (k < 63) {
        int q = k - 3, j = q / 6, r = q % 6, a = r % 3;
        float xx = (a == 0) ? x0 : ((a == 1) ? x1 : x2);
        float arg = (float)(1 << j) * xx;
        v = (r < 3) ? __sinf(arg) : __cosf(arg);
    } else v = 0.0f;
    return v;
}
__device__ __forceinline__ float de_val(int k, float d0, float d1, float d2) {
    float v;
    if (k < 3) v = (k == 0) ? d0 : ((k == 1) ? d1 : d2);
    else if (k < 27) {
        int q = k - 3, j = q / 6, r = q % 6, a = r % 3;
        float xx = (a == 0) ? d0 : ((a == 1) ? d1 : d2);
        float arg = (float)(1 << j) * xx;
        v = (r < 3) ? __sinf(arg) : __cosf(arg);
    } else v = 0.0f;
    return v;
}

// ---- MFMA helpers ----
__device__ __forceinline__ f16x8 ldB(const char* wb, int off, int blk, int lane) {
    return *(const f16x8*)(wb + off + blk * 1024 + lane * 16);
}
// act: [16 p][32 k] f16, row stride 64 B, XOR swizzle (p&3)<<4.
__device__ __forceinline__ f16x8 ldA0(const char* act, int lane) {
    int p = lane & 15, g = lane >> 4;
    int byte = (p * 64 + g * 16) ^ ((p & 3) << 4);
    return *(const f16x8*)(act + byte);
}
__device__ __forceinline__ void stD0(char* act, int kcol, f32x4 acc, bool relu, int g4) {
#pragma unroll
    for (int r = 0; r < 4; r++) {
        int p = g4 * 4 + r;
        float v = acc[r];
        if (relu) v = fmaxf(v, 0.0f);
        *(_Float16*)(act + ((p * 64 + kcol * 2) ^ ((p & 3) << 4))) = (_Float16)v;
    }
}

// Batched staging (validated R12): phase 1 issues all independent global
// loads into compile-time-indexed registers; phase 2 packs + ds_writes.
template <int ITERS, int NKS>
__device__ __forceinline__ void stage_fragC(char* wb, int off,
                                            const float* __restrict__ W,
                                            int Krows, int Ncols, int stride,
                                            int tid) {
    float va[ITERS], vb[ITERS];
    unsigned int* dst = (unsigned int*)(wb + off);
#pragma unroll
    for (int j = 0; j < ITERS; j++) {
        int e = tid + 256 * j;
        int m = e & 3;
        int l = (e >> 2) & 63;
        int blk = e >> 8;
        int ks = blk % NKS;
        int n = blk / NKS;
        int c = l & 15, gg = l >> 4;
        int k0 = ks * 32 + gg * 8 + 2 * m;
        int col = 16 * n + c;
        int ka = (k0 < Krows) ? k0 : (Krows - 1);
        int kb = (k0 + 1 < Krows) ? (k0 + 1) : (Krows - 1);
        int cc = (col < Ncols) ? col : (Ncols - 1);
        va[j] = W[ka * stride + cc];
        vb[j] = W[kb * stride + cc];
    }
#pragma unroll
    for (int j = 0; j < ITERS; j++) {
        int e = tid + 256 * j;
        int m = e & 3;
        int l = (e >> 2) & 63;
        int blk = e >> 8;
        dst[blk * 256 + l * 4 + m] = packrn(va[j], vb[j]);
    }
}

#define MFMA16(a, b, c) __builtin_amdgcn_mfma_f32_16x16x32_f16((a), (b), (c), 0, 0, 0)

// 4 waves/block, one cell/block. Encoding A-frags built lane-locally in
// registers; act LDS holds only layer outputs k 0..31 (1 KB/wave).
// LDS/block ~19.5 KB; NO min-waves clamp (R17's ,8 caused catastrophic
// spills: VGPR 32, 147 MB scratch writes). Natural VGPR ~60 -> 8 blocks/CU.
__global__ void __launch_bounds__(256) k_mlp(
    const float* __restrict__ xs, const float* __restrict__ dvs,
    const float* __restrict__ w1g, const float* __restrict__ b1g,
    const float* __restrict__ w2g, const float* __restrict__ b2g,
    const float* __restrict__ w3g, const float* __restrict__ b3g,
    const float* __restrict__ w4g, const float* __restrict__ b4g,
    const float* __restrict__ w5g, const float* __restrict__ b5g,
    const int* __restrict__ offsets, const int* __restrict__ sorted,
    float* __restrict__ out, int P) {
    __shared__ __align__(16) char wB[14336];
    __shared__ __align__(16) char actAll[4][1024];
    __shared__ float bias[160];
    __shared__ float sig[64];
    __shared__ int idxL[64];

    int cell = blockIdx.x;
    int start = offsets[cell], end = offsets[cell + 1];
    if (start >= end) return;
    int tid = threadIdx.x;
    int lane = tid & 63;
    int wid = tid >> 6;
    int cidx = lane & 15;
    int g4 = lane >> 4;

    stage_fragC<4, 2>(wB, 0,     w1g + (size_t)cell * 2016, 63, 32, 32, tid);
    stage_fragC<3, 1>(wB, 4096,  w2g + (size_t)cell * 1056, 32, 33, 33, tid);
    stage_fragC<2, 1>(wB, 7168,  w3g + (size_t)cell * 1024, 32, 32, 32, tid);
    stage_fragC<4, 2>(wB, 9216,  w4g + (size_t)cell * 1888, 59, 32, 32, tid);
    stage_fragC<1, 1>(wB, 13312, w5g + (size_t)cell * 96,   32, 3, 3, tid);
    if (tid < 160) {
        int e = tid;
        float v = 0.0f;
        if (e < 32) v = b1g[(size_t)cell * 32 + e];
        else if (e < 80) { int q = e - 32; v = (q < 33) ? b2g[(size_t)cell * 33 + q] : 0.0f; }
        else if (e < 112) v = b3g[(size_t)cell * 32 + (e - 80)];
        else if (e < 144) v = b4g[(size_t)cell * 32 + (e - 112)];
        else { int q = e - 144; v = (q < 3) ? b5g[(size_t)cell * 3 + q] : 0.0f; }
        bias[e] = v;
    }
    __syncthreads();

    char* buf = actAll[wid];
    float* sigw = sig + (wid << 4);
    int* idxw = idxL + (wid << 4);

    for (int t0 = start + (wid << 4); t0 < end; t0 += 64) {
        int nv = end - t0; if (nv > 16) nv = 16;
        int t = t0 + cidx;
        int idx = sorted[(cidx < nv) ? t : start];
        if (g4 == 0) idxw[cidx] = idx;
        float x0 = xs[idx * 3 + 0], x1 = xs[idx * 3 + 1], x2 = xs[idx * 3 + 2];
        float d0 = dvs[idx * 3 + 0], d1 = dvs[idx * 3 + 1], d2 = dvs[idx * 3 + 2];

        // ---- L1 A-frags lane-local: lane (cidx,g4) computes
        // enc[point cidx][k=8*g4+i] (a0) and [k=32+8*g4+i] (a1).
        f16x8 a0, a1;
#pragma unroll
        for (int i = 0; i < 8; i++) {
            a0[i] = (_Float16)pe_val(8 * g4 + i, x0, x1, x2);
            a1[i] = (_Float16)pe_val(32 + 8 * g4 + i, x0, x1, x2);
        }

        // ---- L1: enc(64) -> 32, relu -> buf k0..31
#pragma unroll
        for (int n = 0; n < 2; n++) {
            float bv = bias[0 + 16 * n + cidx];
            f32x4 acc = {bv, bv, bv, bv};
            acc = MFMA16(a0, ldB(wB, 0, n * 2 + 0, lane), acc);
            acc = MFMA16(a1, ldB(wB, 0, n * 2 + 1, lane), acc);
            stD0(buf, 16 * n + cidx, acc, true, g4);
        }

        // ---- L2: 32 -> 33, relu; col0 -> sigma; cols1..32 -> buf
        {
            f16x8 a2 = ldA0(buf, lane);
#pragma unroll
            for (int n = 0; n < 3; n++) {
                float bv = bias[32 + 16 * n + cidx];
                f32x4 acc = {bv, bv, bv, bv};
                acc = MFMA16(a2, ldB(wB, 4096, n, lane), acc);
                int C = 16 * n + cidx;
                if (C == 0) {
#pragma unroll
                    for (int r = 0; r < 4; r++) sigw[g4 * 4 + r] = fmaxf(acc[r], 0.0f);
                } else if (C <= 32) {
                    stD0(buf, C - 1, acc, true, g4);
                }
            }
        }
        // ---- L3: 32 -> 32, no act -> buf
        {
            f16x8 a3 = ldA0(buf, lane);
#pragma unroll
            for (int n = 0; n < 2; n++) {
                float bv = bias[80 + 16 * n + cidx];
                f32x4 acc = {bv, bv, bv, bv};
                acc = MFMA16(a3, ldB(wB, 7168, n, lane), acc);
                stD0(buf, 16 * n + cidx, acc, false, g4);
            }
        }
        // ---- L4: [h3 (LDS) | dir-enc (registers)] -> 32, relu -> buf
        {
            f16x8 a4a = ldA0(buf, lane);
            f16x8 a4b;
#pragma unroll
            for (int i = 0; i < 8; i++) a4b[i] = (_Float16)de_val(8 * g4 + i, d0, d1, d2);
#pragma unroll
            for (int n = 0; n < 2; n++) {
                float bv = bias[112 + 16 * n + cidx];
                f32x4 acc = {bv, bv, bv, bv};
                acc = MFMA16(a4a, ldB(wB, 9216, n * 2 + 0, lane), acc);
                acc = MFMA16(a4b, ldB(wB, 9216, n * 2 + 1, lane), acc);
                stD0(buf, 16 * n + cidx, acc, true, g4);
            }
        }
        // ---- L5: 32 -> 3, sigmoid; + sigma out
        {
            f16x8 a5 = ldA0(buf, lane);
            float bv = bias[144 + cidx];
            f32x4 acc = {bv, bv, bv, bv};
            acc = MFMA16(a5, ldB(wB, 13312, 0, lane), acc);
            if (cidx < 3) {
#pragma unroll
                for (int r = 0; r < 4; r++) {
                    int p = g4 * 4 + r;
                    if (p < nv) out[(size_t)idxw[p] * 3 + cidx] = 1.0f / (1.0f + __expf(-acc[r]));
                }
            } else if (cidx == 3) {
#pragma unroll
                for (int r = 0; r < 4; r++) {
                    int p = g4 * 4 + r;
                    if (p < nv) out[(size_t)3 * P + idxw[p]] = sigw[p];
                }
            }
        }
    }
}

extern "C" void kernel_launch(void* const* d_in, const int* in_sizes, int n_in,
                              void* d_out, int out_size, void* d_ws, size_t ws_size,
                              hipStream_t stream) {
    const float* xs = (const float*)d_in[0];
    const float* dv = (const float*)d_in[1];
    const float* w1 = (const float*)d_in[2];
    const float* b1 = (const float*)d_in[3];
    const float* w2 = (const float*)d_in[4];
    const float* b2 = (const float*)d_in[5];
    const float* w3 = (const float*)d_in[6];
    const float* b3 = (const float*)d_in[7];
    const float* w4 = (const float*)d_in[8];
    const float* b4 = (const float*)d_in[9];
    const float* w5 = (const float*)d_in[10];
    const float* b5 = (const float*)d_in[11];
    float* out = (float*)d_out;
    int P = in_sizes[0] / 3;

    int* counts = (int*)d_ws;
    int* offsets = counts + 4096;
    int* cursor = offsets + 4104;
    int* sorted = cursor + 4096;
    int* cellid = sorted + P;

    hipMemsetAsync(counts, 0, 4096 * sizeof(int), stream);

    int blk = 256;
    int grd = (P + blk - 1) / blk;
    k_count<<<grd, blk, 0, stream>>>(xs, counts, cellid, out, P);
    k_scan<<<1, 64, 0, stream>>>(counts, offsets, cursor);
    k_scatter<<<grd, blk, 0, stream>>>(cellid, cursor, sorted, P);
    k_mlp<<<NCELL, 256, 0, stream>>>(xs, dv, w1, b1, w2, b2, w3, b3, w4, b4, w5, b5,
                                     offsets, sorted, out, P);
}